// Round 1
// baseline (9929.452 us; speedup 1.0000x reference)
//
#include <hip/hip_runtime.h>
#include <hip/hip_bf16.h>

#define D_S 128
#define D_F 1000
#define NH  4
#define NP  3
#define NB  4
#define SL  512
#define BL  (NB*SL)   // 2048 token rows

// ============================ gather ============================
// Per (b,l): mu = tok_mu[tok]+pos_mu[l]; iv = exp(-log_var); alpha = sigmoid(raw); feats copy.
__global__ __launch_bounds__(256) void gather_kernel(
    const int* __restrict__ tokens, const float* __restrict__ tok_mu,
    const float* __restrict__ tok_lv, const float* __restrict__ tok_ra,
    const float* __restrict__ tok_f, const float* __restrict__ pos_mu,
    float* __restrict__ mu, float* __restrict__ iv,
    float* __restrict__ alpha, float* __restrict__ feats)
{
    int row = blockIdx.x;            // b*SL + l
    int l = row & (SL - 1);
    int tok = tokens[row];
    for (int d = threadIdx.x; d < D_S; d += 256) {
        mu[row*D_S + d] = tok_mu[tok*D_S + d] + pos_mu[l*D_S + d];
        iv[row*D_S + d] = expf(-tok_lv[tok*D_S + d]);
    }
    if (threadIdx.x == 0)
        alpha[row] = 1.f / (1.f + expf(-tok_ra[tok]));
    for (int f = threadIdx.x; f < D_F; f += 256)
        feats[row*D_F + f] = tok_f[tok*D_F + f];
}

// ============================ generic TN GEMM ============================
// C[M,N] = A[M,K] @ Bt[N,K]^T  (+ epilogue)
// EPI: 0 = store, 1 = store(+bias), 2 = store gelu(+bias), 3 = C += (+bias), 4 = C += tanh(+bias)
template<int EPI>
__global__ __launch_bounds__(256) void gemm_tn(
    const float* __restrict__ A, const float* __restrict__ Bt,
    const float* __restrict__ bias, float* __restrict__ C,
    int M, int N, int K)
{
    const int BM = 64, BN = 64, BK = 16;
    __shared__ float As[BK][BM + 4];   // +4 pad keeps 16B alignment for float4 reads
    __shared__ float Bs[BK][BN + 4];
    int tid = threadIdx.x;
    int tx = tid & 15, ty = tid >> 4;              // 16x16 thread tile, 4x4 per thread
    int bm = blockIdx.y * BM, bn = blockIdx.x * BN;
    int lr = tid >> 2;                 // 0..63: tile row (A) / tile col (B)
    int lk = (tid & 3) * 4;            // 0,4,8,12: k offset
    float acc[4][4] = {};
    for (int kk = 0; kk < K; kk += BK) {
        int gr = bm + lr;
        int gn = bn + lr;
        #pragma unroll
        for (int i = 0; i < 4; i++) {
            int gk = kk + lk + i;
            As[lk + i][lr] = (gr < M && gk < K) ? A[(long)gr*K + gk] : 0.f;
            Bs[lk + i][lr] = (gn < N && gk < K) ? Bt[(long)gn*K + gk] : 0.f;
        }
        __syncthreads();
        #pragma unroll
        for (int k = 0; k < BK; k++) {
            float4 av = *(const float4*)&As[k][ty << 2];
            float4 bv = *(const float4*)&Bs[k][tx << 2];
            float a[4] = {av.x, av.y, av.z, av.w};
            float b[4] = {bv.x, bv.y, bv.z, bv.w};
            #pragma unroll
            for (int i = 0; i < 4; i++)
                #pragma unroll
                for (int j = 0; j < 4; j++)
                    acc[i][j] += a[i] * b[j];
        }
        __syncthreads();
    }
    #pragma unroll
    for (int i = 0; i < 4; i++) {
        int r = bm + (ty << 2) + i;
        if (r >= M) continue;
        #pragma unroll
        for (int j = 0; j < 4; j++) {
            int c = bn + (tx << 2) + j;
            if (c >= N) continue;
            float v = acc[i][j];
            long idx = (long)r*N + c;
            if (EPI == 0)      C[idx] = v;
            else if (EPI == 1) C[idx] = v + bias[c];
            else if (EPI == 2) { v += bias[c]; C[idx] = 0.5f*v*(1.f + erff(v*0.70710678118654752f)); }
            else if (EPI == 3) C[idx] += v + bias[c];
            else if (EPI == 4) C[idx] += tanhf(v + bias[c]);
        }
    }
}

// ============================ NN GEMM for mh ============================
// Per batch b (blockIdx.z): rows r = h*SL+l of w[b] [2048,512] @ feats[b] [512,1000].
// Causal: w[...,j]=0 for j>l, so K-tiles beyond bm%SL+64 are skipped (rows in a 64-tile share h).
// Output written permuted: mh[((b*SL+l)*NH + h)*D_F + f]  (== [B,L,H*D_F] for the Whead GEMM).
__global__ __launch_bounds__(256) void gemm_mh(
    const float* __restrict__ Wfull, const float* __restrict__ feats,
    float* __restrict__ mh)
{
    const int BM = 64, BN = 64, BK = 16;
    const int M = NH*SL, N = D_F, K = SL;
    __shared__ float As[BK][BM + 4];
    __shared__ float Bs[BK][BN + 4];
    int b = blockIdx.z;
    const float* A  = Wfull + (long)b*M*K;
    const float* Bm = feats + (long)b*SL*D_F;
    int tid = threadIdx.x;
    int tx = tid & 15, ty = tid >> 4;
    int bm = blockIdx.y * BM, bn = blockIdx.x * BN;
    int kmax = (bm & (SL - 1)) + BM;               // causal bound (multiple of 16)
    int lrA = tid >> 2, lkA = (tid & 3) * 4;
    int lkB = tid >> 4, lnB = (tid & 15) * 4;
    float acc[4][4] = {};
    for (int kk = 0; kk < kmax; kk += BK) {
        #pragma unroll
        for (int i = 0; i < 4; i++)
            As[lkA + i][lrA] = A[(long)(bm + lrA)*K + kk + lkA + i];
        #pragma unroll
        for (int j = 0; j < 4; j++) {
            int gn = bn + lnB + j;
            Bs[lkB][lnB + j] = (gn < N) ? Bm[(long)(kk + lkB)*N + gn] : 0.f;
        }
        __syncthreads();
        #pragma unroll
        for (int k = 0; k < BK; k++) {
            float4 av = *(const float4*)&As[k][ty << 2];
            float4 bv = *(const float4*)&Bs[k][tx << 2];
            float a[4] = {av.x, av.y, av.z, av.w};
            float bb[4] = {bv.x, bv.y, bv.z, bv.w};
            #pragma unroll
            for (int i = 0; i < 4; i++)
                #pragma unroll
                for (int j = 0; j < 4; j++)
                    acc[i][j] += a[i] * bb[j];
        }
        __syncthreads();
    }
    int h = bm / SL;
    #pragma unroll
    for (int i = 0; i < 4; i++) {
        int r = bm + (ty << 2) + i;
        int l = r & (SL - 1);
        long orow = ((long)(b*SL + l)*NH + h) * D_F;
        #pragma unroll
        for (int j = 0; j < 4; j++) {
            int c = bn + (tx << 2) + j;
            if (c < N) mh[orow + c] = acc[i][j];
        }
    }
}

// ============================ attention: mahal + compositing scan ============================
// Block = (l, h, b). 4 waves: wave w handles j = w, w+4, ... <= l.
// mahal = sum_d iv[b,j,d]*(q[b,h,l,d]-mu[b,j,d])^2  (== q^2.iv - 2q.mu_iv + mu2, exactly)
// Then wave 0 does the log-space transmittance scan and writes w[b,h,l,:].
__global__ __launch_bounds__(256) void attn_kernel(
    const float* __restrict__ q,      // [BL, NH*D_S]
    const float* __restrict__ mu,     // [BL, D_S]
    const float* __restrict__ iv,     // [BL, D_S]
    const float* __restrict__ alpha,  // [BL]
    const float* __restrict__ log_tau,
    float* __restrict__ wout)         // [B,H,L,L]
{
    int l = blockIdx.x, h = blockIdx.y, b = blockIdx.z;
    int tid = threadIdx.x, lane = tid & 63, wid = tid >> 6;
    __shared__ float qs[D_S];
    __shared__ float eff_s[SL];
    float scale = -0.5f / expf(log_tau[0]);
    if (tid < D_S)
        qs[tid] = q[(long)(b*SL + l)*(NH*D_S) + h*D_S + tid];
    for (int j = tid; j < SL; j += 256) eff_s[j] = 0.f;
    __syncthreads();
    for (int j = wid; j <= l; j += 4) {
        const float* mup = mu + (long)(b*SL + j)*D_S;
        const float* ivp = iv + (long)(b*SL + j)*D_S;
        float t0 = qs[lane]      - mup[lane];
        float t1 = qs[lane + 64] - mup[lane + 64];
        float s = ivp[lane]*t0*t0 + ivp[lane + 64]*t1*t1;
        #pragma unroll
        for (int o = 32; o > 0; o >>= 1) s += __shfl_xor(s, o);
        if (lane == 0) {
            float Kv = expf(scale * s);
            float e  = fminf(alpha[b*SL + j] * Kv, 1.f - 1e-6f);
            eff_s[j] = e;
        }
    }
    __syncthreads();
    if (wid == 0) {
        float carry = 0.f;
        long orow = (((long)b*NH + h)*SL + l)*SL;
        for (int c = 0; c < SL/64; c++) {
            int j = c*64 + lane;
            float e  = eff_s[j];
            float le = log1pf(-e);
            float sc = le;                        // inclusive scan
            #pragma unroll
            for (int o = 1; o < 64; o <<= 1) {
                float v = __shfl_up(sc, o);
                if (lane >= o) sc += v;
            }
            float logT = carry + sc - le;         // exclusive prefix
            wout[orow + j] = e * expf(logT);
            carry += __shfl(sc, 63);
        }
    }
}

// ============================ x = concat(feats, meaning) ============================
__global__ __launch_bounds__(256) void build_x(
    const float* __restrict__ feats, const float* __restrict__ meaning,
    float* __restrict__ x)
{
    long i = (long)blockIdx.x*256 + threadIdx.x;   // over BL*D_F
    if (i < (long)BL*D_F) {
        int r = (int)(i / D_F), c = (int)(i % D_F);
        x[(long)r*2*D_F + c]       = feats[i];
        x[(long)r*2*D_F + D_F + c] = meaning[i];
    }
}

// ============================ alpha gate ============================
__global__ __launch_bounds__(256) void gate_kernel(
    const float* __restrict__ x, const float* __restrict__ Wg,
    const float* __restrict__ bg, float* __restrict__ alpha)
{
    int r = blockIdx.x;
    int tid = threadIdx.x, lane = tid & 63, wid = tid >> 6;
    float s = 0.f;
    for (int c = tid; c < 2*D_F; c += 256)
        s += x[(long)r*2*D_F + c] * Wg[c];
    #pragma unroll
    for (int o = 32; o > 0; o >>= 1) s += __shfl_xor(s, o);
    __shared__ float red[4];
    if (lane == 0) red[wid] = s;
    __syncthreads();
    if (tid == 0) {
        float t = red[0] + red[1] + red[2] + red[3] + bg[0];
        alpha[r] *= 1.f / (1.f + expf(-t));
    }
}

// ============================ layernorm ============================
__global__ __launch_bounds__(256) void ln_kernel(
    const float* __restrict__ x, const float* __restrict__ g,
    const float* __restrict__ bsh, float* __restrict__ o, int D)
{
    int r = blockIdx.x;
    const float* xr = x + (long)r*D;
    int tid = threadIdx.x, lane = tid & 63, wid = tid >> 6;
    float s = 0.f, s2 = 0.f;
    for (int c = tid; c < D; c += 256) { float v = xr[c]; s += v; s2 += v*v; }
    #pragma unroll
    for (int o = 32; o > 0; o >>= 1) { s += __shfl_xor(s, o); s2 += __shfl_xor(s2, o); }
    __shared__ float rs[4], rs2[4], stat[2];
    if (lane == 0) { rs[wid] = s; rs2[wid] = s2; }
    __syncthreads();
    if (tid == 0) {
        float a = rs[0] + rs[1] + rs[2] + rs[3];
        float bb = rs2[0] + rs2[1] + rs2[2] + rs2[3];
        float mean = a / D;
        float var = bb / D - mean*mean;
        if (var < 0.f) var = 0.f;
        stat[0] = mean;
        stat[1] = 1.f / sqrtf(var + 1e-5f);
    }
    __syncthreads();
    float mean = stat[0], inv = stat[1];
    for (int c = tid; c < D; c += 256)
        o[(long)r*D + c] = (xr[c] - mean)*inv*g[c] + bsh[c];
}

// ============================ launch ============================
extern "C" void kernel_launch(void* const* d_in, const int* in_sizes, int n_in,
                              void* d_out, int out_size, void* d_ws, size_t ws_size,
                              hipStream_t stream)
{
    const int*   tokens  = (const int*)  d_in[0];
    const float* tok_mu  = (const float*)d_in[1];
    const float* tok_lv  = (const float*)d_in[2];
    const float* tok_ra  = (const float*)d_in[3];
    const float* tok_f   = (const float*)d_in[4];
    const float* pos_mu  = (const float*)d_in[5];
    const float* log_tau = (const float*)d_in[6];
    const float* Wq      = (const float*)d_in[7];
    const float* bq      = (const float*)d_in[8];
    const float* Whead   = (const float*)d_in[9];
    const float* bhead   = (const float*)d_in[10];
    const float* Wmu     = (const float*)d_in[11];
    const float* bmu     = (const float*)d_in[12];
    const float* Wg      = (const float*)d_in[13];
    const float* bg      = (const float*)d_in[14];
    const float* ln_g    = (const float*)d_in[15];
    const float* ln_b    = (const float*)d_in[16];
    const float* W1      = (const float*)d_in[17];
    const float* b1      = (const float*)d_in[18];
    const float* W2      = (const float*)d_in[19];
    const float* b2      = (const float*)d_in[20];
    const float* lnf_g   = (const float*)d_in[21];
    const float* lnf_b   = (const float*)d_in[22];
    const float* Wlm     = (const float*)d_in[23];
    float* out = (float*)d_out;

    // workspace carve (floats). Total ~88.6 MB.
    float* ws = (float*)d_ws;
    size_t off = 0;
    auto alloc = [&](size_t n) { float* p = ws + off; off += n; return p; };
    float* mu      = alloc((size_t)BL*D_S);          // 262144
    float* iv      = alloc((size_t)BL*D_S);          // 262144
    float* alpha   = alloc((size_t)BL);              // 2048
    float* feats   = alloc((size_t)BL*D_F);          // 2.048M
    float* q       = alloc((size_t)BL*NH*D_S);       // 1.049M
    float* w       = alloc((size_t)NB*NH*SL*SL);     // 4.194M  (aliased by hbuf & y)
    float* mh      = alloc((size_t)BL*NH*D_F);       // 8.192M  (aliased by t)
    float* meaning = alloc((size_t)BL*D_F);          // 2.048M
    float* x       = alloc((size_t)BL*2*D_F);        // 4.096M
    float* hbuf = w;    // LN(x) [BL,2000]; w is dead during the update phase
    float* y    = w;    // final LN(meaning) [BL,1000]; w dead after last mh
    float* t    = mh;   // FFN mid [BL,4000]; mh dead after meaning GEMM

    gather_kernel<<<BL, 256, 0, stream>>>(tokens, tok_mu, tok_lv, tok_ra, tok_f,
                                          pos_mu, mu, iv, alpha, feats);

    for (int p = 0; p < NP; p++) {
        // q = mu @ Wq.T + bq            [2048, 512], K=128
        gemm_tn<1><<<dim3(8, 32), 256, 0, stream>>>(mu, Wq, bq, q, BL, NH*D_S, D_S);
        // w = compositing weights       [B,H,L,L]
        attn_kernel<<<dim3(SL, NH, NB), 256, 0, stream>>>(q, mu, iv, alpha, log_tau, w);
        // mh = w @ feats  (permuted out to [B,L,H*D_F])
        gemm_mh<<<dim3(16, 32, NB), 256, 0, stream>>>(w, feats, mh);
        // meaning = mh @ Whead.T + bhead   [2048, 1000], K=4000
        gemm_tn<1><<<dim3(16, 32), 256, 0, stream>>>(mh, Whead, bhead, meaning, BL, D_F, NH*D_F);
        if (p < NP - 1) {
            build_x<<<(BL*D_F + 255)/256, 256, 0, stream>>>(feats, meaning, x);
            // alpha *= sigmoid(x . Wg[p] + bg[p])
            gate_kernel<<<BL, 256, 0, stream>>>(x, Wg + (size_t)p*2*D_F, bg + p, alpha);
            // mu += tanh(x @ Wmu[p].T + bmu[p])   [2048, 128], K=2000
            gemm_tn<4><<<dim3(2, 32), 256, 0, stream>>>(x, Wmu + (size_t)p*D_S*2*D_F,
                                                        bmu + (size_t)p*D_S, mu, BL, D_S, 2*D_F);
            // h = LN(x)
            ln_kernel<<<BL, 256, 0, stream>>>(x, ln_g + (size_t)p*2*D_F, ln_b + (size_t)p*2*D_F,
                                              hbuf, 2*D_F);
            // t = gelu(h @ W1[p].T + b1[p])   [2048, 4000], K=2000
            gemm_tn<2><<<dim3(63, 32), 256, 0, stream>>>(hbuf, W1 + (size_t)p*4*D_F*2*D_F,
                                                         b1 + (size_t)p*4*D_F, t, BL, 4*D_F, 2*D_F);
            // feats += t @ W2[p].T + b2[p]    [2048, 1000], K=4000
            gemm_tn<3><<<dim3(16, 32), 256, 0, stream>>>(t, W2 + (size_t)p*D_F*4*D_F,
                                                         b2 + (size_t)p*D_F, feats, BL, D_F, 4*D_F);
        }
    }
    // y = LN(meaning) ; out = y @ Wlm.T   [2048, 32000], K=1000
    ln_kernel<<<BL, 256, 0, stream>>>(meaning, lnf_g, lnf_b, y, D_F);
    gemm_tn<0><<<dim3(500, 32), 256, 0, stream>>>(y, Wlm, nullptr, out, BL, 32000, D_F);
}